// Round 12
// baseline (197.863 us; speedup 1.0000x reference)
//
#include <hip/hip_runtime.h>
#include <hip/hip_bf16.h>
#include <math.h>

#define B_  2
#define T_  2048
#define D_  1024
#define H_  16
#define HD_ 64

typedef __attribute__((ext_vector_type(8))) short short8;
typedef __attribute__((ext_vector_type(4))) float f32x4;

#if __has_builtin(__builtin_amdgcn_exp2f)
#define EXP2F __builtin_amdgcn_exp2f
#else
#define EXP2F exp2f
#endif

__device__ __forceinline__ ushort f2bf(float x) {
    unsigned u = __builtin_bit_cast(unsigned, x);
    return (ushort)((u + 0x7FFFu + ((u >> 16) & 1u)) >> 16);  // RTNE
}

// round-half-up bf16 pair pack
__device__ __forceinline__ unsigned pack_bf2_fast(float a, float b) {
    unsigned ua = __builtin_bit_cast(unsigned, a) + 0x8000u;
    unsigned ub = __builtin_bit_cast(unsigned, b) + 0x8000u;
    return (ua >> 16) | (ub & 0xFFFF0000u);
}

__device__ __forceinline__ void load_lds_16B(const ushort* g, ushort* l) {
    __builtin_amdgcn_global_load_lds(
        (const __attribute__((address_space(1))) unsigned*)g,
        (__attribute__((address_space(3))) unsigned*)l, 16, 0, 0);
}

// ---------------------------------------------------------------------------
// Merged prep: [0,512) cast x->bf16; [512,1280) transpose Wqkv; [1280,1536)
// transpose Wout. Wt stores are 16B/lane.
// ---------------------------------------------------------------------------
__global__ __launch_bounds__(256)
void prep_kernel(const float* __restrict__ x, ushort* __restrict__ xb,
                 const float* __restrict__ Wqkv, ushort* __restrict__ Wqkvt,
                 const float* __restrict__ Wout, ushort* __restrict__ Woutt)
{
    __shared__ ushort Ts[64][65];
    const int bid = blockIdx.x;

    if (bid < 512) {
        const int n4 = (B_ * T_ * D_) / 4;
        for (int i = bid * 256 + threadIdx.x; i < n4; i += 512 * 256) {
            float4 v = ((const float4*)x)[i];
            ushort4 o = { f2bf(v.x), f2bf(v.y), f2bf(v.z), f2bf(v.w) };
            ((ushort4*)xb)[i] = o;
        }
        return;
    }

    const float* W; ushort* Wt; int K, M, m0, k0;
    if (bid < 1280) {
        const int t = bid - 512;
        W = Wqkv; Wt = Wqkvt; K = D_; M = 3 * D_;
        m0 = (t % 48) * 64; k0 = (t / 48) * 64;
    } else {
        const int t = bid - 1280;
        W = Wout; Wt = Woutt; K = D_; M = D_;
        m0 = (t % 16) * 64; k0 = (t / 16) * 64;
    }

    const int tr = threadIdx.x >> 4;
    const int tc = threadIdx.x & 15;
    #pragma unroll
    for (int it = 0; it < 4; it++) {
        int k = tr + it * 16;
        float4 v = *(const float4*)&W[(size_t)(k0 + k) * M + m0 + tc * 4];
        Ts[tc * 4 + 0][k] = f2bf(v.x);
        Ts[tc * 4 + 1][k] = f2bf(v.y);
        Ts[tc * 4 + 2][k] = f2bf(v.z);
        Ts[tc * 4 + 3][k] = f2bf(v.w);
    }
    __syncthreads();
    #pragma unroll
    for (int it = 0; it < 2; it++) {
        const int mr  = (threadIdx.x >> 3) + it * 32;
        const int seg = (threadIdx.x & 7) * 8;
        short8 v;
        #pragma unroll
        for (int r = 0; r < 8; r++) v[r] = (short)Ts[mr][seg + r];
        *(short8*)&Wt[(size_t)(m0 + mr) * K + k0 + seg] = v;
    }
}

// ---------------------------------------------------------------------------
// QKV GEMM (round-9 known-good): 128x128 tile, coalesced LDS-staged epilogue.
// ---------------------------------------------------------------------------
__global__ __launch_bounds__(256, 4)
void gemm_qkv(const ushort* __restrict__ A, const ushort* __restrict__ Bt,
              const float* __restrict__ bias,
              ushort* __restrict__ Qg, ushort* __restrict__ Kg,
              ushort* __restrict__ Vtg)
{
    const int K = D_;
    __shared__ __align__(16) ushort lds[16384];
    ushort* Asl = lds;
    ushort* Bsl = lds + 8192;

    const int tid = threadIdx.x;
    const int w  = tid >> 6, L = tid & 63;
    const int lt = L & 15, lq = L >> 4;
    const int wr = w >> 1, wc = w & 1;
    const int m0 = blockIdx.x * 128, n0 = blockIdx.y * 128;
    const int rsub = L >> 3;
    const int pgr  = L & 7;

    f32x4 acc[4][4] = {};

    for (int k0 = 0; k0 < K; k0 += 64) {
        __syncthreads();
        #pragma unroll
        for (int j = 0; j < 4; j++) {
            const int row  = (w * 4 + j) * 8 + rsub;
            const int gran = pgr ^ rsub;
            load_lds_16B(A  + (size_t)(n0 + row) * K + k0 + gran * 8,
                         &Asl[row * 64 + pgr * 8]);
            load_lds_16B(Bt + (size_t)(m0 + row) * K + k0 + gran * 8,
                         &Bsl[row * 64 + pgr * 8]);
        }
        __syncthreads();

        #pragma unroll
        for (int ks = 0; ks < 2; ks++) {
            short8 af[4], bf[4];
            #pragma unroll
            for (int i = 0; i < 4; i++) {
                const int ra = wr * 64 + i * 16 + lt;
                af[i] = *(const short8*)&Asl[ra * 64 + (((ks * 4 + lq) ^ (ra & 7)) * 8)];
                const int rb = wc * 64 + i * 16 + lt;
                bf[i] = *(const short8*)&Bsl[rb * 64 + (((ks * 4 + lq) ^ (rb & 7)) * 8)];
            }
            #pragma unroll
            for (int i = 0; i < 4; i++)
                #pragma unroll
                for (int j = 0; j < 4; j++)
                    acc[i][j] = __builtin_amdgcn_mfma_f32_16x16x32_bf16(af[i], bf[j], acc[i][j], 0, 0, 0);
        }
    }

    __syncthreads();
    const int s  = m0 >> 10;
    const int h0 = (m0 & 1023) >> 6;
    const float qs = (s == 0) ? 0.18033688011112042f : 1.0f;   // 0.125*log2(e)

    if (s < 2) {
        #pragma unroll
        for (int j = 0; j < 4; j++) {
            const int m  = wc * 64 + j * 16 + lt;
            const float bv = bias[m0 + m];
            #pragma unroll
            for (int i = 0; i < 4; i++) {
                const int n = wr * 64 + i * 16 + lq * 4;
                #pragma unroll
                for (int r = 0; r < 4; r++)
                    lds[(n + r) * 128 + m] = f2bf((acc[i][j][r] + bv) * qs);
            }
        }
        __syncthreads();
        ushort* dst = (s == 0 ? Qg : Kg);
        #pragma unroll
        for (int it = 0; it < 8; it++) {
            const int g   = tid + it * 256;
            const int row = g >> 4, c = g & 15;
            const int n = n0 + row;
            const int b = n >> 11, t = n & 2047;
            const int h = h0 + (c >> 3), d = (c & 7) * 8;
            short8 v = *(const short8*)&lds[row * 128 + c * 8];
            *(short8*)&dst[((size_t)(b * H_ + h) * T_ + t) * HD_ + d] = v;
        }
    } else {
        #pragma unroll
        for (int j = 0; j < 4; j++) {
            const int m  = wc * 64 + j * 16 + lt;
            const float bv = bias[m0 + m];
            #pragma unroll
            for (int i = 0; i < 4; i++) {
                const int n = wr * 64 + i * 16 + lq * 4;
                uint2 pk = { pack_bf2_fast(acc[i][j][0] + bv, acc[i][j][1] + bv),
                             pack_bf2_fast(acc[i][j][2] + bv, acc[i][j][3] + bv) };
                *(uint2*)&lds[m * 128 + n] = pk;
            }
        }
        __syncthreads();
        const int b = n0 >> 11, t0 = n0 & 2047;
        #pragma unroll
        for (int it = 0; it < 8; it++) {
            const int g   = tid + it * 256;
            const int row = g >> 4, c = g & 15;
            const int h = h0 + (row >> 6), d = row & 63;
            short8 v = *(const short8*)&lds[row * 128 + c * 8];
            *(short8*)&Vtg[((size_t)(b * H_ + h) * HD_ + d) * T_ + t0 + c * 8] = v;
        }
    }
}

// ---------------------------------------------------------------------------
// Out GEMM (round-9 known-good): swapped operands, direct float4 stores.
// ---------------------------------------------------------------------------
__global__ __launch_bounds__(256, 4)
void gemm_out(const ushort* __restrict__ A, const ushort* __restrict__ Bt,
              const float* __restrict__ bias, float* __restrict__ C)
{
    const int K = D_, M = D_;
    __shared__ __align__(16) ushort lds[8192 + 4096];
    ushort* Asl = lds;
    ushort* Bsl = lds + 8192;

    const int tid = threadIdx.x;
    const int w  = tid >> 6, L = tid & 63;
    const int lt = L & 15, lq = L >> 4;
    const int wr = w >> 1, wc = w & 1;
    const int m0 = blockIdx.x * 64, n0 = blockIdx.y * 128;
    const int rsub = L >> 3;
    const int pgr  = L & 7;

    f32x4 acc[2][4] = {};

    for (int k0 = 0; k0 < K; k0 += 64) {
        __syncthreads();
        #pragma unroll
        for (int j = 0; j < 4; j++) {
            const int row  = (w * 4 + j) * 8 + rsub;
            const int gran = pgr ^ rsub;
            load_lds_16B(A + (size_t)(n0 + row) * K + k0 + gran * 8,
                         &Asl[row * 64 + pgr * 8]);
        }
        #pragma unroll
        for (int j = 0; j < 2; j++) {
            const int row  = (w * 2 + j) * 8 + rsub;
            const int gran = pgr ^ rsub;
            load_lds_16B(Bt + (size_t)(m0 + row) * K + k0 + gran * 8,
                         &Bsl[row * 64 + pgr * 8]);
        }
        __syncthreads();

        #pragma unroll
        for (int ks = 0; ks < 2; ks++) {
            short8 wf[2], yf[4];
            #pragma unroll
            for (int j = 0; j < 2; j++) {
                const int rb = wc * 32 + j * 16 + lt;
                wf[j] = *(const short8*)&Bsl[rb * 64 + (((ks * 4 + lq) ^ (rb & 7)) * 8)];
            }
            #pragma unroll
            for (int i = 0; i < 4; i++) {
                const int ra = wr * 64 + i * 16 + lt;
                yf[i] = *(const short8*)&Asl[ra * 64 + (((ks * 4 + lq) ^ (ra & 7)) * 8)];
            }
            #pragma unroll
            for (int j = 0; j < 2; j++)
                #pragma unroll
                for (int i = 0; i < 4; i++)
                    acc[j][i] = __builtin_amdgcn_mfma_f32_16x16x32_bf16(wf[j], yf[i], acc[j][i], 0, 0, 0);
        }
    }

    #pragma unroll
    for (int j = 0; j < 2; j++) {
        const int mbase = m0 + wc * 32 + j * 16 + lq * 4;
        const float4 bv = *(const float4*)&bias[mbase];
        #pragma unroll
        for (int i = 0; i < 4; i++) {
            const int n = n0 + wr * 64 + i * 16 + lt;
            float4 o = { acc[j][i][0] + bv.x, acc[j][i][1] + bv.y,
                         acc[j][i][2] + bv.z, acc[j][i][3] + bv.w };
            *(float4*)&C[(size_t)n * M + mbase] = o;
        }
    }
}

// ---------------------------------------------------------------------------
// MFMA flash attention v9 — hybrid staging.
// K staged in LDS via global_load_lds (shared by all 4 waves: S^T A-operand
// is wave-invariant). V fragments read DIRECT global->VGPR per chunk: in the
// S^T form Vt[d][key] B-fragments are 16B-contiguous and identical across
// waves; per-kb V tile (16 KB) fits L1, and the QK+exp chain covers the L2
// latency. LDS = 21 KB -> 4 blocks/CU truly co-resident (vs 2 at r9).
// One 64-q-row tile per block (1024 blocks); flip = (y>>3)^z balances CUs.
// ---------------------------------------------------------------------------
__global__ __launch_bounds__(256, 4)
void attn_mfma(const ushort* __restrict__ Qg, const ushort* __restrict__ Kg,
               const ushort* __restrict__ Vtg, ushort* __restrict__ yb)
{
    const int h = blockIdx.y, b = blockIdx.z;
    const int flip = ((blockIdx.y >> 3) ^ blockIdx.z) & 1;
    const int qb = flip ? blockIdx.x : (31 - blockIdx.x);
    const int tid = threadIdx.x;
    const int w  = tid >> 6, L = tid & 63;
    const int lt = L & 15, lq = L >> 4;

    __shared__ __align__(16) ushort Ks[128 * 64];   // 16 KB
    __shared__ __align__(16) ushort Ps[4][640];     //  5 KB

    const size_t bh = (size_t)(b * H_ + h);
    const ushort* Qbase  = Qg  + bh * T_ * HD_;
    const ushort* Kbase  = Kg  + bh * T_ * HD_;
    const ushort* Vf     = Vtg + bh * HD_ * T_ + (size_t)lt * T_ + lq * 8; // +d16*16*T +key

    const int q_glob = qb * 64 + w * 16 + lt;
    const short8 qf0 = *(const short8*)(Qbase + (size_t)q_glob * HD_ + lq * 8);
    const short8 qf1 = *(const short8*)(Qbase + (size_t)q_glob * HD_ + 32 + lq * 8);

    f32x4 acc_o[4] = {};
    float lsum = 0.f;

    const int krow = tid >> 3, kpg = tid & 7;
    const int nk = (qb + 2) >> 1;

    for (int kb = 0; kb < nk; kb++) {
        __syncthreads();
        #pragma unroll
        for (int rr = 0; rr < 4; rr++) {
            const int row = krow + 32 * rr;
            load_lds_16B(Kbase + (size_t)(kb * 128 + row) * HD_ + (kpg ^ (row & 7)) * 8,
                         &Ks[row * 64 + kpg * 8]);
        }
        __syncthreads();

        const bool last = (kb == nk - 1);
        const int ksN = (!last || (qb & 1)) ? 4 : 2;
        const int mk0 = last ? ((qb & 1) ? 2 : 0) : 4;

        for (int ks = 0; ks < ksN; ks++) {
            const int key0 = kb * 128 + ks * 32;
            // ---- V fragments straight from global (issued early; used after
            //      the QK/exp chain so L1/L2 latency is covered) ----
            const ushort* vp = Vf + key0;
            short8 vf0 = *(const short8*)(vp);
            short8 vf1 = *(const short8*)(vp + 16 * T_);
            short8 vf2 = *(const short8*)(vp + 32 * T_);
            short8 vf3 = *(const short8*)(vp + 48 * T_);

            const int row0 = (2 * ks) * 16 + lt;
            const int row1 = row0 + 16;
            short8 a00 = *(const short8*)&Ks[row0 * 64 + ((lq ^ (row0 & 7)) * 8)];
            short8 a01 = *(const short8*)&Ks[row0 * 64 + (((4 + lq) ^ (row0 & 7)) * 8)];
            short8 a10 = *(const short8*)&Ks[row1 * 64 + ((lq ^ (row1 & 7)) * 8)];
            short8 a11 = *(const short8*)&Ks[row1 * 64 + (((4 + lq) ^ (row1 & 7)) * 8)];
            f32x4 c0 = {}, c1 = {};
            c0 = __builtin_amdgcn_mfma_f32_16x16x32_bf16(a00, qf0, c0, 0, 0, 0);
            c0 = __builtin_amdgcn_mfma_f32_16x16x32_bf16(a01, qf1, c0, 0, 0, 0);
            c1 = __builtin_amdgcn_mfma_f32_16x16x32_bf16(a10, qf0, c1, 0, 0, 0);
            c1 = __builtin_amdgcn_mfma_f32_16x16x32_bf16(a11, qf1, c1, 0, 0, 0);

            float p[8];
            #pragma unroll
            for (int r = 0; r < 4; r++) { p[r] = EXP2F(c0[r]); p[4 + r] = EXP2F(c1[r]); }
            if (ks >= mk0) {   // diagonal chunk: causal mask
                const int kq = key0 + lq * 4;
                #pragma unroll
                for (int r = 0; r < 4; r++) {
                    if (kq + r > q_glob)      p[r] = 0.f;
                    if (kq + 16 + r > q_glob) p[4 + r] = 0.f;
                }
            }
            lsum += ((p[0] + p[1]) + (p[2] + p[3])) + ((p[4] + p[5]) + (p[6] + p[7]));
            *(uint2*)&Ps[w][lt * 40 + lq * 4] =
                (uint2){ pack_bf2_fast(p[0], p[1]), pack_bf2_fast(p[2], p[3]) };
            *(uint2*)&Ps[w][lt * 40 + 16 + lq * 4] =
                (uint2){ pack_bf2_fast(p[4], p[5]), pack_bf2_fast(p[6], p[7]) };

            short8 pf = *(const short8*)&Ps[w][lt * 40 + lq * 8];

            acc_o[0] = __builtin_amdgcn_mfma_f32_16x16x32_bf16(pf, vf0, acc_o[0], 0, 0, 0);
            acc_o[1] = __builtin_amdgcn_mfma_f32_16x16x32_bf16(pf, vf1, acc_o[1], 0, 0, 0);
            acc_o[2] = __builtin_amdgcn_mfma_f32_16x16x32_bf16(pf, vf2, acc_o[2], 0, 0, 0);
            acc_o[3] = __builtin_amdgcn_mfma_f32_16x16x32_bf16(pf, vf3, acc_o[3], 0, 0, 0);
        }
    }

    // ---- deferred row-sum reduction (q = lt, across 4 lq lanes) ----
    lsum += __shfl_xor(lsum, 16, 64);
    lsum += __shfl_xor(lsum, 32, 64);
    const float inv = 1.0f / lsum;

    float linv[4];
    #pragma unroll
    for (int r = 0; r < 4; r++) linv[r] = __shfl(inv, lq * 4 + r, 64);

    ushort* ybase = yb + (size_t)(b * T_ + qb * 64 + w * 16) * D_ + h * HD_;
    #pragma unroll
    for (int r = 0; r < 4; r++)
        #pragma unroll
        for (int dt = 0; dt < 4; dt++)
            ybase[(size_t)(lq * 4 + r) * D_ + dt * 16 + lt] = f2bf(acc_o[dt][r] * linv[r]);
}

// ---------------------------------------------------------------------------
extern "C" void kernel_launch(void* const* d_in, const int* in_sizes, int n_in,
                              void* d_out, int out_size, void* d_ws, size_t ws_size,
                              hipStream_t stream)
{
    const float* x    = (const float*)d_in[0];
    const float* Wqkv = (const float*)d_in[1];
    const float* bqkv = (const float*)d_in[2];
    const float* Wout = (const float*)d_in[3];
    const float* bout = (const float*)d_in[4];
    float* out = (float*)d_out;

    char* ws = (char*)d_ws;
    const size_t NT = (size_t)B_ * T_;
    ushort* xb     = (ushort*)ws;
    ushort* Wqkvt  = (ushort*)(ws + NT * D_ * 2);
    ushort* Woutt  = (ushort*)(ws + NT * D_ * 2 + (size_t)3 * D_ * D_ * 2);
    char*   p      = ws + NT * D_ * 2 + (size_t)4 * D_ * D_ * 2;
    const size_t qkv_elems = (size_t)B_ * H_ * T_ * HD_;
    ushort* Qg  = (ushort*)p;
    ushort* Kg  = (ushort*)(p + qkv_elems * 2);
    ushort* Vtg = (ushort*)(p + qkv_elems * 4);
    ushort* yb  = (ushort*)(p + qkv_elems * 6);

    prep_kernel<<<1536, 256, 0, stream>>>(x, xb, Wqkv, Wqkvt, Wout, Woutt);

    gemm_qkv<<<dim3(3 * D_ / 128, NT / 128), 256, 0, stream>>>(
        xb, Wqkvt, bqkv, Qg, Kg, Vtg);

    attn_mfma<<<dim3(32, H_, B_), 256, 0, stream>>>(Qg, Kg, Vtg, yb);

    gemm_out<<<dim3(D_ / 64, NT / 128), 256, 0, stream>>>(
        yb, Woutt, bout, out);
}

// Round 13
// 172.051 us; speedup vs baseline: 1.1500x; 1.1500x over previous
//
#include <hip/hip_runtime.h>
#include <hip/hip_bf16.h>
#include <math.h>

#define B_  2
#define T_  2048
#define D_  1024
#define H_  16
#define HD_ 64

typedef __attribute__((ext_vector_type(8))) short short8;
typedef __attribute__((ext_vector_type(8))) _Float16 half8;
typedef __attribute__((ext_vector_type(4))) float f32x4;

#if __has_builtin(__builtin_amdgcn_exp2f)
#define EXP2F __builtin_amdgcn_exp2f
#else
#define EXP2F exp2f
#endif

__device__ __forceinline__ ushort f2bf(float x) {
    unsigned u = __builtin_bit_cast(unsigned, x);
    return (ushort)((u + 0x7FFFu + ((u >> 16) & 1u)) >> 16);  // RTNE
}

// round-half-up bf16 pair pack
__device__ __forceinline__ unsigned pack_bf2_fast(float a, float b) {
    unsigned ua = __builtin_bit_cast(unsigned, a) + 0x8000u;
    unsigned ub = __builtin_bit_cast(unsigned, b) + 0x8000u;
    return (ua >> 16) | (ub & 0xFFFF0000u);
}

// fp16 pair pack: single v_cvt_pkrtz_f16_f32
__device__ __forceinline__ unsigned pack_h2(float a, float b) {
    return __builtin_bit_cast(unsigned, __builtin_amdgcn_cvt_pkrtz(a, b));
}

__device__ __forceinline__ void load_lds_16B(const ushort* g, ushort* l) {
    __builtin_amdgcn_global_load_lds(
        (const __attribute__((address_space(1))) unsigned*)g,
        (__attribute__((address_space(3))) unsigned*)l, 16, 0, 0);
}

// ---------------------------------------------------------------------------
// Merged prep: [0,512) cast x->bf16; [512,1280) transpose Wqkv; [1280,1536)
// transpose Wout. Wt stores are 16B/lane.
// ---------------------------------------------------------------------------
__global__ __launch_bounds__(256)
void prep_kernel(const float* __restrict__ x, ushort* __restrict__ xb,
                 const float* __restrict__ Wqkv, ushort* __restrict__ Wqkvt,
                 const float* __restrict__ Wout, ushort* __restrict__ Woutt)
{
    __shared__ ushort Ts[64][65];
    const int bid = blockIdx.x;

    if (bid < 512) {
        const int n4 = (B_ * T_ * D_) / 4;
        for (int i = bid * 256 + threadIdx.x; i < n4; i += 512 * 256) {
            float4 v = ((const float4*)x)[i];
            ushort4 o = { f2bf(v.x), f2bf(v.y), f2bf(v.z), f2bf(v.w) };
            ((ushort4*)xb)[i] = o;
        }
        return;
    }

    const float* W; ushort* Wt; int K, M, m0, k0;
    if (bid < 1280) {
        const int t = bid - 512;
        W = Wqkv; Wt = Wqkvt; K = D_; M = 3 * D_;
        m0 = (t % 48) * 64; k0 = (t / 48) * 64;
    } else {
        const int t = bid - 1280;
        W = Wout; Wt = Woutt; K = D_; M = D_;
        m0 = (t % 16) * 64; k0 = (t / 16) * 64;
    }

    const int tr = threadIdx.x >> 4;
    const int tc = threadIdx.x & 15;
    #pragma unroll
    for (int it = 0; it < 4; it++) {
        int k = tr + it * 16;
        float4 v = *(const float4*)&W[(size_t)(k0 + k) * M + m0 + tc * 4];
        Ts[tc * 4 + 0][k] = f2bf(v.x);
        Ts[tc * 4 + 1][k] = f2bf(v.y);
        Ts[tc * 4 + 2][k] = f2bf(v.z);
        Ts[tc * 4 + 3][k] = f2bf(v.w);
    }
    __syncthreads();
    #pragma unroll
    for (int it = 0; it < 2; it++) {
        const int mr  = (threadIdx.x >> 3) + it * 32;
        const int seg = (threadIdx.x & 7) * 8;
        short8 v;
        #pragma unroll
        for (int r = 0; r < 8; r++) v[r] = (short)Ts[mr][seg + r];
        *(short8*)&Wt[(size_t)(m0 + mr) * K + k0 + seg] = v;
    }
}

// ---------------------------------------------------------------------------
// QKV GEMM: 128x128 tile, coalesced LDS-staged epilogue. Q,K bf16 [b,h,t,d]
// (Q pre-scaled by 0.125*log2e); Vt stored FP16 [b,h,d,t] (feeds f16 PV MFMA;
// fp16 is more accurate than bf16 for these +-3-range values).
// ---------------------------------------------------------------------------
__global__ __launch_bounds__(256, 4)
void gemm_qkv(const ushort* __restrict__ A, const ushort* __restrict__ Bt,
              const float* __restrict__ bias,
              ushort* __restrict__ Qg, ushort* __restrict__ Kg,
              ushort* __restrict__ Vtg)
{
    const int K = D_;
    __shared__ __align__(16) ushort lds[16384];
    ushort* Asl = lds;
    ushort* Bsl = lds + 8192;

    const int tid = threadIdx.x;
    const int w  = tid >> 6, L = tid & 63;
    const int lt = L & 15, lq = L >> 4;
    const int wr = w >> 1, wc = w & 1;
    const int m0 = blockIdx.x * 128, n0 = blockIdx.y * 128;
    const int rsub = L >> 3;
    const int pgr  = L & 7;

    f32x4 acc[4][4] = {};

    for (int k0 = 0; k0 < K; k0 += 64) {
        __syncthreads();
        #pragma unroll
        for (int j = 0; j < 4; j++) {
            const int row  = (w * 4 + j) * 8 + rsub;
            const int gran = pgr ^ rsub;
            load_lds_16B(A  + (size_t)(n0 + row) * K + k0 + gran * 8,
                         &Asl[row * 64 + pgr * 8]);
            load_lds_16B(Bt + (size_t)(m0 + row) * K + k0 + gran * 8,
                         &Bsl[row * 64 + pgr * 8]);
        }
        __syncthreads();

        #pragma unroll
        for (int ks = 0; ks < 2; ks++) {
            short8 af[4], bf[4];
            #pragma unroll
            for (int i = 0; i < 4; i++) {
                const int ra = wr * 64 + i * 16 + lt;
                af[i] = *(const short8*)&Asl[ra * 64 + (((ks * 4 + lq) ^ (ra & 7)) * 8)];
                const int rb = wc * 64 + i * 16 + lt;
                bf[i] = *(const short8*)&Bsl[rb * 64 + (((ks * 4 + lq) ^ (rb & 7)) * 8)];
            }
            #pragma unroll
            for (int i = 0; i < 4; i++)
                #pragma unroll
                for (int j = 0; j < 4; j++)
                    acc[i][j] = __builtin_amdgcn_mfma_f32_16x16x32_bf16(af[i], bf[j], acc[i][j], 0, 0, 0);
        }
    }

    __syncthreads();
    const int s  = m0 >> 10;
    const int h0 = (m0 & 1023) >> 6;
    const float qs = (s == 0) ? 0.18033688011112042f : 1.0f;   // 0.125*log2(e)

    if (s < 2) {
        #pragma unroll
        for (int j = 0; j < 4; j++) {
            const int m  = wc * 64 + j * 16 + lt;
            const float bv = bias[m0 + m];
            #pragma unroll
            for (int i = 0; i < 4; i++) {
                const int n = wr * 64 + i * 16 + lq * 4;
                #pragma unroll
                for (int r = 0; r < 4; r++)
                    lds[(n + r) * 128 + m] = f2bf((acc[i][j][r] + bv) * qs);
            }
        }
        __syncthreads();
        ushort* dst = (s == 0 ? Qg : Kg);
        #pragma unroll
        for (int it = 0; it < 8; it++) {
            const int g   = tid + it * 256;
            const int row = g >> 4, c = g & 15;
            const int n = n0 + row;
            const int b = n >> 11, t = n & 2047;
            const int h = h0 + (c >> 3), d = (c & 7) * 8;
            short8 v = *(const short8*)&lds[row * 128 + c * 8];
            *(short8*)&dst[((size_t)(b * H_ + h) * T_ + t) * HD_ + d] = v;
        }
    } else {
        #pragma unroll
        for (int j = 0; j < 4; j++) {
            const int m  = wc * 64 + j * 16 + lt;
            const float bv = bias[m0 + m];
            #pragma unroll
            for (int i = 0; i < 4; i++) {
                const int n = wr * 64 + i * 16 + lq * 4;
                uint2 pk = { pack_h2(acc[i][j][0] + bv, acc[i][j][1] + bv),
                             pack_h2(acc[i][j][2] + bv, acc[i][j][3] + bv) };
                *(uint2*)&lds[m * 128 + n] = pk;
            }
        }
        __syncthreads();
        const int b = n0 >> 11, t0 = n0 & 2047;
        #pragma unroll
        for (int it = 0; it < 8; it++) {
            const int g   = tid + it * 256;
            const int row = g >> 4, c = g & 15;
            const int h = h0 + (row >> 6), d = row & 63;
            short8 v = *(const short8*)&lds[row * 128 + c * 8];
            *(short8*)&Vtg[((size_t)(b * H_ + h) * HD_ + d) * T_ + t0 + c * 8] = v;
        }
    }
}

// ---------------------------------------------------------------------------
// Out GEMM (round-9 known-good): swapped operands, direct float4 stores.
// ---------------------------------------------------------------------------
__global__ __launch_bounds__(256, 4)
void gemm_out(const ushort* __restrict__ A, const ushort* __restrict__ Bt,
              const float* __restrict__ bias, float* __restrict__ C)
{
    const int K = D_, M = D_;
    __shared__ __align__(16) ushort lds[8192 + 4096];
    ushort* Asl = lds;
    ushort* Bsl = lds + 8192;

    const int tid = threadIdx.x;
    const int w  = tid >> 6, L = tid & 63;
    const int lt = L & 15, lq = L >> 4;
    const int wr = w >> 1, wc = w & 1;
    const int m0 = blockIdx.x * 64, n0 = blockIdx.y * 128;
    const int rsub = L >> 3;
    const int pgr  = L & 7;

    f32x4 acc[2][4] = {};

    for (int k0 = 0; k0 < K; k0 += 64) {
        __syncthreads();
        #pragma unroll
        for (int j = 0; j < 4; j++) {
            const int row  = (w * 4 + j) * 8 + rsub;
            const int gran = pgr ^ rsub;
            load_lds_16B(A + (size_t)(n0 + row) * K + k0 + gran * 8,
                         &Asl[row * 64 + pgr * 8]);
        }
        #pragma unroll
        for (int j = 0; j < 2; j++) {
            const int row  = (w * 2 + j) * 8 + rsub;
            const int gran = pgr ^ rsub;
            load_lds_16B(Bt + (size_t)(m0 + row) * K + k0 + gran * 8,
                         &Bsl[row * 64 + pgr * 8]);
        }
        __syncthreads();

        #pragma unroll
        for (int ks = 0; ks < 2; ks++) {
            short8 wf[2], yf[4];
            #pragma unroll
            for (int j = 0; j < 2; j++) {
                const int rb = wc * 32 + j * 16 + lt;
                wf[j] = *(const short8*)&Bsl[rb * 64 + (((ks * 4 + lq) ^ (rb & 7)) * 8)];
            }
            #pragma unroll
            for (int i = 0; i < 4; i++) {
                const int ra = wr * 64 + i * 16 + lt;
                yf[i] = *(const short8*)&Asl[ra * 64 + (((ks * 4 + lq) ^ (ra & 7)) * 8)];
            }
            #pragma unroll
            for (int j = 0; j < 2; j++)
                #pragma unroll
                for (int i = 0; i < 4; i++)
                    acc[j][i] = __builtin_amdgcn_mfma_f32_16x16x32_bf16(wf[j], yf[i], acc[j][i], 0, 0, 0);
        }
    }

    #pragma unroll
    for (int j = 0; j < 2; j++) {
        const int mbase = m0 + wc * 32 + j * 16 + lq * 4;
        const float4 bv = *(const float4*)&bias[mbase];
        #pragma unroll
        for (int i = 0; i < 4; i++) {
            const int n = n0 + wr * 64 + i * 16 + lt;
            float4 o = { acc[j][i][0] + bv.x, acc[j][i][1] + bv.y,
                         acc[j][i][2] + bv.z, acc[j][i][3] + bv.w };
            *(float4*)&C[(size_t)n * M + mbase] = o;
        }
    }
}

// ---------------------------------------------------------------------------
// MFMA flash attention v10 — v4 structure + DOUBLE-BUFFERED staging + fp16 P/V.
// r9 v4 analysis: 44.5 us ~= staging(16) + MFMA(17) + VALU(14): pipes fully
// serialized by the per-iter barrier/vmcnt drain. Fix: KB=64 steps, 2 LDS
// buffers (37 KB total -> same 4 blocks/CU); loads for kb+1 issued right
// after the barrier, so the next barrier's vmcnt(0) drain finds them landed.
// P packed with single-instr v_cvt_pkrtz (fp16); V stored fp16; PV uses
// mfma_f32_16x16x32_f16. QK stays bf16.
// ---------------------------------------------------------------------------
__global__ __launch_bounds__(256, 4)
void attn_mfma(const ushort* __restrict__ Qg, const ushort* __restrict__ Kg,
               const ushort* __restrict__ Vtg, ushort* __restrict__ yb)
{
    const int h = blockIdx.y, b = blockIdx.z;
    const int flip = ((blockIdx.y >> 3) ^ blockIdx.z) & 1;
    const int qb = flip ? blockIdx.x : (31 - blockIdx.x);
    const int tid = threadIdx.x;
    const int w  = tid >> 6, L = tid & 63;
    const int lt = L & 15, lq = L >> 4;
    const int kswz = lt & 7;

    __shared__ __align__(16) ushort Ks [2][64 * 64];   // 16 KB (bf16 K)
    __shared__ __align__(16) ushort Vts[2][64 * 64];   // 16 KB (fp16 V)
    __shared__ __align__(16) ushort Ps [4][640];       //  5 KB (fp16 P)

    const size_t bh = (size_t)(b * H_ + h);
    const ushort* Qbase  = Qg  + bh * T_ * HD_;
    const ushort* Kbase  = Kg  + bh * T_ * HD_;
    const ushort* Vtbase = Vtg + bh * HD_ * T_;

    const int q_in   = w * 16 + lt;          // in-tile q row
    const int q_glob = qb * 64 + q_in;
    const short8 qf0 = *(const short8*)(Qbase + (size_t)q_glob * HD_ + lq * 8);
    const short8 qf1 = *(const short8*)(Qbase + (size_t)q_glob * HD_ + 32 + lq * 8);

    f32x4 acc_o[4] = {};
    float lsum = 0.f;

    const int srow = tid >> 3, spg = tid & 7;
    const int nk = qb + 1;                   // 64-key steps

    // ---- prologue: stage step 0 into buffer 0 ----
    #pragma unroll
    for (int rr = 0; rr < 2; rr++) {
        const int r = srow + 32 * rr;
        load_lds_16B(Kbase + (size_t)r * HD_ + ((spg ^ (r & 7)) * 8),
                     &Ks[0][r * 64 + spg * 8]);
        load_lds_16B(Vtbase + (size_t)r * T_ + ((spg ^ (r & 7)) * 8),
                     &Vts[0][r * 64 + spg * 8]);
    }

    for (int kb = 0; kb < nk; kb++) {
        const int cur = kb & 1;
        __syncthreads();   // drains loads of buf[cur]; prior reads of buf[1-cur] done

        if (kb + 1 < nk) {   // issue next tile's loads now; overlap with compute
            const int nxt = cur ^ 1;
            #pragma unroll
            for (int rr = 0; rr < 2; rr++) {
                const int r = srow + 32 * rr;
                load_lds_16B(Kbase + (size_t)((kb + 1) * 64 + r) * HD_ + ((spg ^ (r & 7)) * 8),
                             &Ks[nxt][r * 64 + spg * 8]);
                load_lds_16B(Vtbase + (size_t)r * T_ + (kb + 1) * 64 + ((spg ^ (r & 7)) * 8),
                             &Vts[nxt][r * 64 + spg * 8]);
            }
        }

        const bool diag = (kb == nk - 1);
        const int ksN = diag ? ((w >> 1) + 1) : 2;   // per-wave chunk count on diag
        const int mkc = diag ? (w >> 1) : 2;         // chunk needing the mask

        for (int ks = 0; ks < ksN; ks++) {
            const int row0 = ks * 32 + lt;
            const int row1 = row0 + 16;
            short8 a00 = *(const short8*)&Ks[cur][row0 * 64 + ((lq ^ kswz) * 8)];
            short8 a01 = *(const short8*)&Ks[cur][row0 * 64 + (((4 + lq) ^ kswz) * 8)];
            short8 a10 = *(const short8*)&Ks[cur][row1 * 64 + ((lq ^ kswz) * 8)];
            short8 a11 = *(const short8*)&Ks[cur][row1 * 64 + (((4 + lq) ^ kswz) * 8)];
            f32x4 c0 = {}, c1 = {};
            c0 = __builtin_amdgcn_mfma_f32_16x16x32_bf16(a00, qf0, c0, 0, 0, 0);
            c0 = __builtin_amdgcn_mfma_f32_16x16x32_bf16(a01, qf1, c0, 0, 0, 0);
            c1 = __builtin_amdgcn_mfma_f32_16x16x32_bf16(a10, qf0, c1, 0, 0, 0);
            c1 = __builtin_amdgcn_mfma_f32_16x16x32_bf16(a11, qf1, c1, 0, 0, 0);

            float p[8];
            #pragma unroll
            for (int r = 0; r < 4; r++) { p[r] = EXP2F(c0[r]); p[4 + r] = EXP2F(c1[r]); }
            if (ks == mkc) {                 // diagonal chunk: causal mask (in-tile)
                const int key0 = ks * 32 + lq * 4;
                #pragma unroll
                for (int r = 0; r < 4; r++) {
                    if (key0 + r > q_in)      p[r] = 0.f;
                    if (key0 + 16 + r > q_in) p[4 + r] = 0.f;
                }
            }
            lsum += ((p[0] + p[1]) + (p[2] + p[3])) + ((p[4] + p[5]) + (p[6] + p[7]));
            *(uint2*)&Ps[w][lt * 40 + lq * 4] =
                (uint2){ pack_h2(p[0], p[1]), pack_h2(p[2], p[3]) };
            *(uint2*)&Ps[w][lt * 40 + 16 + lq * 4] =
                (uint2){ pack_h2(p[4], p[5]), pack_h2(p[6], p[7]) };

            half8 pf = __builtin_bit_cast(half8,
                *(const short8*)&Ps[w][lt * 40 + lq * 8]);

            #pragma unroll
            for (int dt = 0; dt < 4; dt++) {
                const int vr = dt * 16 + lt;
                half8 vf = __builtin_bit_cast(half8,
                    *(const short8*)&Vts[cur][vr * 64 + (((ks * 4 + lq) ^ kswz) * 8)]);
                acc_o[dt] = __builtin_amdgcn_mfma_f32_16x16x32_f16(pf, vf, acc_o[dt], 0, 0, 0);
            }
        }
    }

    // ---- deferred row-sum reduction (q = lt, across 4 lq lanes) ----
    lsum += __shfl_xor(lsum, 16, 64);
    lsum += __shfl_xor(lsum, 32, 64);
    const float inv = 1.0f / lsum;

    float linv[4];
    #pragma unroll
    for (int r = 0; r < 4; r++) linv[r] = __shfl(inv, lq * 4 + r, 64);

    ushort* ybase = yb + (size_t)(b * T_ + qb * 64 + w * 16) * D_ + h * HD_;
    #pragma unroll
    for (int r = 0; r < 4; r++)
        #pragma unroll
        for (int dt = 0; dt < 4; dt++)
            ybase[(size_t)(lq * 4 + r) * D_ + dt * 16 + lt] = f2bf(acc_o[dt][r] * linv[r]);
}

// ---------------------------------------------------------------------------
extern "C" void kernel_launch(void* const* d_in, const int* in_sizes, int n_in,
                              void* d_out, int out_size, void* d_ws, size_t ws_size,
                              hipStream_t stream)
{
    const float* x    = (const float*)d_in[0];
    const float* Wqkv = (const float*)d_in[1];
    const float* bqkv = (const float*)d_in[2];
    const float* Wout = (const float*)d_in[3];
    const float* bout = (const float*)d_in[4];
    float* out = (float*)d_out;

    char* ws = (char*)d_ws;
    const size_t NT = (size_t)B_ * T_;
    ushort* xb     = (ushort*)ws;
    ushort* Wqkvt  = (ushort*)(ws + NT * D_ * 2);
    ushort* Woutt  = (ushort*)(ws + NT * D_ * 2 + (size_t)3 * D_ * D_ * 2);
    char*   p      = ws + NT * D_ * 2 + (size_t)4 * D_ * D_ * 2;
    const size_t qkv_elems = (size_t)B_ * H_ * T_ * HD_;
    ushort* Qg  = (ushort*)p;
    ushort* Kg  = (ushort*)(p + qkv_elems * 2);
    ushort* Vtg = (ushort*)(p + qkv_elems * 4);
    ushort* yb  = (ushort*)(p + qkv_elems * 6);

    prep_kernel<<<1536, 256, 0, stream>>>(x, xb, Wqkv, Wqkvt, Wout, Woutt);

    gemm_qkv<<<dim3(3 * D_ / 128, NT / 128), 256, 0, stream>>>(
        xb, Wqkvt, bqkv, Qg, Kg, Vtg);

    attn_mfma<<<dim3(32, H_, B_), 256, 0, stream>>>(Qg, Kg, Vtg, yb);

    gemm_out<<<dim3(D_ / 64, NT / 128), 256, 0, stream>>>(
        yb, Woutt, bout, out);
}